// Round 9
// baseline (133.260 us; speedup 1.0000x reference)
//
#include <hip/hip_runtime.h>
#include <cmath>

#define NB 8
#define DIM 4096
#define NHQ 32
#define NHKV 8
#define NDH 128
#define MAXSEQ 4096
#define STARTPOS 4095
#define QKV_COLS 6144   // 4096 q + 1024 k + 1024 v
#define RCHUNK 64       // rows per split-K chunk
#define NRC 64          // 4096 / 64
#define SCALE 0.08838834764831845f  // 1/sqrt(128)
#define NCHUNK 64       // attn chunks per batch
#define CPOS 64         // t positions per attn chunk

#define DOT4(k, qq) ((k).x*(qq).x + (k).y*(qq).y + (k).z*(qq).z + (k).w*(qq).w)

// ---------------------------------------------------------------------------
// Kernel 1: QKV projection partials.  grid = 12 col-tiles * 64 row-chunks.
__global__ __launch_bounds__(256) void qkv_partial_k(
    const float* __restrict__ x, const float* __restrict__ wq,
    const float* __restrict__ wk, const float* __restrict__ wv,
    float* __restrict__ part) {
  int bid = blockIdx.x;
  int ct = bid % 12, rc = bid / 12;
  int tid = threadIdx.x;
  const float* W; int ldw; int colbase;
  int gcolbase = ct * 512;
  if (ct < 8)       { W = wq; ldw = NHQ * NDH;  colbase = gcolbase; }
  else if (ct < 10) { W = wk; ldw = NHKV * NDH; colbase = gcolbase - 4096; }
  else              { W = wv; ldw = NHKV * NDH; colbase = gcolbase - 5120; }

  __shared__ __align__(16) float xs[RCHUNK][8];
  int rbase = rc * RCHUNK;
  for (int i = tid; i < RCHUNK * 8; i += 256) {
    int b = i >> 6, r = i & 63;
    xs[r][b] = x[b * DIM + rbase + r];
  }
  __syncthreads();

  int col = colbase + tid * 2;
  const float* wp = W + (size_t)rbase * ldw + col;
  float2 acc[8];
#pragma unroll
  for (int b = 0; b < 8; b++) { acc[b].x = 0.f; acc[b].y = 0.f; }

#pragma unroll 8
  for (int r = 0; r < RCHUNK; r++) {
    float2 w2 = *(const float2*)wp; wp += ldw;
    float4 xa = *(const float4*)&xs[r][0];
    float4 xb = *(const float4*)&xs[r][4];
    acc[0].x += xa.x * w2.x; acc[0].y += xa.x * w2.y;
    acc[1].x += xa.y * w2.x; acc[1].y += xa.y * w2.y;
    acc[2].x += xa.z * w2.x; acc[2].y += xa.z * w2.y;
    acc[3].x += xa.w * w2.x; acc[3].y += xa.w * w2.y;
    acc[4].x += xb.x * w2.x; acc[4].y += xb.x * w2.y;
    acc[5].x += xb.y * w2.x; acc[5].y += xb.y * w2.y;
    acc[6].x += xb.z * w2.x; acc[6].y += xb.z * w2.y;
    acc[7].x += xb.w * w2.x; acc[7].y += xb.w * w2.y;
  }
  int gcol = gcolbase + tid * 2;
#pragma unroll
  for (int b = 0; b < 8; b++)
    *(float2*)&part[((size_t)rc * 8 + b) * QKV_COLS + gcol] = acc[b];
}

// ---------------------------------------------------------------------------
// Kernel 2: reduce partials + bias + RoPE (pos = STARTPOS).  49152 threads.
__global__ __launch_bounds__(256) void qkv_reduce_rope_k(
    const float* __restrict__ part, const float* __restrict__ bq,
    const float* __restrict__ bk, const float* __restrict__ bv,
    float* __restrict__ qws, float* __restrict__ kws, float* __restrict__ vws) {
  int idx = blockIdx.x * 256 + threadIdx.x;
  int b = idx / QKV_COLS, col = idx % QKV_COLS;
  float s = 0.f;
#pragma unroll 8
  for (int rcc = 0; rcc < NRC; rcc++)
    s += part[((size_t)rcc * 8 + b) * QKV_COLS + col];
  float bias = (col < 4096) ? bq[col] : (col < 5120 ? bk[col - 4096] : bv[col - 5120]);
  s += bias;
  float outv = s;
  if (col < 5120) {  // q or k -> RoPE
    int dim = col & 127;
    int i2 = dim & ~1;
    float theta = powf(10000.f, -(float)i2 * (1.f / 128.f));
    float ang = (float)STARTPOS * theta;
    float c = cosf(ang), sn = sinf(ang);
    float other = __shfl_xor(s, 1);
    if ((col & 1) == 0) outv = s * c - other * sn;   // xr*cos - xi*sin
    else                outv = other * sn + s * c;   // xr*sin + xi*cos
  }
  if (col < 4096)       qws[b * 4096 + col] = outv;
  else if (col < 5120)  kws[b * 1024 + (col - 4096)] = outv;
  else                  vws[b * 1024 + (col - 5120)] = outv;
}

// ---------------------------------------------------------------------------
// Kernel 3 (v8): branch-free high-TLP attention.
// grid = 8 b * 64 chunks of 64 t = 512 blocks; 512 thr = 8 waves;
// __launch_bounds__(512,4) -> 2 blocks/CU = 16 waves/CU.
// Wave pair (2p, 2p+1) owns hkv pair p: half-wave = hkv, s32 = 16B slice;
// wave parity = t&1.  Every wave-load = contiguous 1KB of K or V.
// Streaming loops contain NO branches and NO cross-lane ops except two
// pipelined quad-shfls; octet reduction deferred; STARTPOS fixed up after.
__global__ __launch_bounds__(512, 4) void attn_pair_k(
    const float* __restrict__ qws, const float* __restrict__ kws,
    const float* __restrict__ vws, const float* __restrict__ ck,
    const float* __restrict__ cv, float* __restrict__ pm,
    float* __restrict__ pl, float* __restrict__ pacc) {
  int bid = blockIdx.x;
  int chunk = bid & 63, b = bid >> 6;
  int tid = threadIdx.x;
  int w = tid >> 6, lane = tid & 63;
  int half = lane >> 5, s32 = lane & 31;
  int pairid = w >> 1, parity = w & 1;
  int hkv = pairid * 2 + half;
  int t0 = chunk * CPOS;

  __shared__ float sbuf[NHKV][4][CPOS + 1];        // scores -> P
  __shared__ __align__(16) float axl[4][64][20];   // odd-wave acc dump

  // q fragments: this lane's hkv, its 16B slice, 4 heads
  const float* qb = qws + ((size_t)b * NHQ + hkv * 4) * NDH + s32 * 4;
  float4 qf0 = *(const float4*)(qb + 0 * NDH);
  float4 qf1 = *(const float4*)(qb + 1 * NDH);
  float4 qf2 = *(const float4*)(qb + 2 * NDH);
  float4 qf3 = *(const float4*)(qb + 3 * NDH);

  const float* kbase = ck + ((size_t)(b * MAXSEQ + t0) * NHKV + hkv) * NDH + s32 * 4;
  const float* vbase = cv + ((size_t)(b * MAXSEQ + t0) * NHKV + hkv) * NDH + s32 * 4;

  // ---- Phase A: K stream (32 t per wave: t_local = 2*j + parity) ----
  float s_t[32];
#pragma unroll
  for (int ii = 0; ii < 32; ii += 8) {
    float4 kf[8];
#pragma unroll
    for (int u = 0; u < 8; u++)
      kf[u] = *(const float4*)(kbase + (size_t)(2 * (ii + u) + parity) * 1024);
#pragma unroll
    for (int u = 0; u < 8; u++) {
      float p0 = DOT4(kf[u], qf0);
      float p1 = DOT4(kf[u], qf1);
      float p2 = DOT4(kf[u], qf2);
      float p3 = DOT4(kf[u], qf3);
      p0 += __shfl_xor(p0, 1); p0 += __shfl_xor(p0, 2);
      p1 += __shfl_xor(p1, 1); p1 += __shfl_xor(p1, 2);
      p2 += __shfl_xor(p2, 1); p2 += __shfl_xor(p2, 2);
      p3 += __shfl_xor(p3, 1); p3 += __shfl_xor(p3, 2);
      int hsel = s32 & 3;
      s_t[ii + u] = (hsel == 0) ? p0 : (hsel == 1) ? p1 : (hsel == 2) ? p2 : p3;
    }
  }
  // deferred octet reduction: 32 independent 3-shfl chains
#pragma unroll
  for (int j = 0; j < 32; j++) {
    float v = s_t[j];
    v += __shfl_xor(v, 4); v += __shfl_xor(v, 8); v += __shfl_xor(v, 16);
    if (s32 < 4) sbuf[hkv][s32][2 * j + parity] = v * SCALE;
  }
  __syncthreads();

  // ---- fix-up: the new token's scores (t = STARTPOS, only chunk 63) ----
  if (chunk == 63 && tid < NHQ) {
    int hq = tid, hk = hq >> 2;
    const float4* qp = (const float4*)(qws + ((size_t)b * NHQ + hq) * NDH);
    const float4* kp = (const float4*)(kws + ((size_t)b * NHKV + hk) * NDH);
    float s = 0.f;
#pragma unroll
    for (int j = 0; j < 32; j++) { float4 a = qp[j], c = kp[j]; s += DOT4(a, c); }
    sbuf[hk][hq & 3][63] = s * SCALE;
  }
  __syncthreads();

  // ---- Phase B: per-head softmax partials over 64 t; normalize in place ----
  {
    int hq = tid >> 4, sub = tid & 15;
    int hk = hq >> 2, hh = hq & 3;
    float e0 = sbuf[hk][hh][sub];
    float e1 = sbuf[hk][hh][sub + 16];
    float e2 = sbuf[hk][hh][sub + 32];
    float e3 = sbuf[hk][hh][sub + 48];
    float m = fmaxf(fmaxf(e0, e1), fmaxf(e2, e3));
    m = fmaxf(m, __shfl_xor(m, 1));
    m = fmaxf(m, __shfl_xor(m, 2));
    m = fmaxf(m, __shfl_xor(m, 4));
    m = fmaxf(m, __shfl_xor(m, 8));
    float q0 = expf(e0 - m), q1 = expf(e1 - m), q2 = expf(e2 - m), q3 = expf(e3 - m);
    float l = q0 + q1 + q2 + q3;
    l += __shfl_xor(l, 1);
    l += __shfl_xor(l, 2);
    l += __shfl_xor(l, 4);
    l += __shfl_xor(l, 8);
    if (sub == 0) {
      pm[(size_t)bid * NHQ + hq] = m;
      pl[(size_t)bid * NHQ + hq] = l;
    }
    sbuf[hk][hh][sub] = q0;
    sbuf[hk][hh][sub + 16] = q1;
    sbuf[hk][hh][sub + 32] = q2;
    sbuf[hk][hh][sub + 48] = q3;
  }
  __syncthreads();

  // ---- Phase C: V stream, register accumulators (same t-split) ----
  float4 acc0 = {0.f, 0.f, 0.f, 0.f};
  float4 acc1 = {0.f, 0.f, 0.f, 0.f};
  float4 acc2 = {0.f, 0.f, 0.f, 0.f};
  float4 acc3 = {0.f, 0.f, 0.f, 0.f};
#pragma unroll
  for (int ii = 0; ii < 32; ii += 8) {
    float4 vf[8];
#pragma unroll
    for (int u = 0; u < 8; u++)
      vf[u] = *(const float4*)(vbase + (size_t)(2 * (ii + u) + parity) * 1024);
#pragma unroll
    for (int u = 0; u < 8; u++) {
      int tl = 2 * (ii + u) + parity;
      float pp0 = sbuf[hkv][0][tl];
      float pp1 = sbuf[hkv][1][tl];
      float pp2 = sbuf[hkv][2][tl];
      float pp3 = sbuf[hkv][3][tl];
      acc0.x += pp0 * vf[u].x; acc0.y += pp0 * vf[u].y;
      acc0.z += pp0 * vf[u].z; acc0.w += pp0 * vf[u].w;
      acc1.x += pp1 * vf[u].x; acc1.y += pp1 * vf[u].y;
      acc1.z += pp1 * vf[u].z; acc1.w += pp1 * vf[u].w;
      acc2.x += pp2 * vf[u].x; acc2.y += pp2 * vf[u].y;
      acc2.z += pp2 * vf[u].z; acc2.w += pp2 * vf[u].w;
      acc3.x += pp3 * vf[u].x; acc3.y += pp3 * vf[u].y;
      acc3.z += pp3 * vf[u].z; acc3.w += pp3 * vf[u].w;
    }
  }
  // ---- fix-up: new token's V (t = STARTPOS is t_local 63, parity 1) ----
  if (chunk == 63 && parity == 1) {
    float4 vold = *(const float4*)(vbase + (size_t)63 * 1024);
    float4 vnew = *(const float4*)(vws + ((size_t)b * NHKV + hkv) * NDH + s32 * 4);
    float d0 = vnew.x - vold.x, d1 = vnew.y - vold.y,
          d2 = vnew.z - vold.z, d3 = vnew.w - vold.w;
    float pp0 = sbuf[hkv][0][63], pp1 = sbuf[hkv][1][63],
          pp2 = sbuf[hkv][2][63], pp3 = sbuf[hkv][3][63];
    acc0.x += pp0 * d0; acc0.y += pp0 * d1; acc0.z += pp0 * d2; acc0.w += pp0 * d3;
    acc1.x += pp1 * d0; acc1.y += pp1 * d1; acc1.z += pp1 * d2; acc1.w += pp1 * d3;
    acc2.x += pp2 * d0; acc2.y += pp2 * d1; acc2.z += pp2 * d2; acc2.w += pp2 * d3;
    acc3.x += pp3 * d0; acc3.y += pp3 * d1; acc3.z += pp3 * d2; acc3.w += pp3 * d3;
  }

  // ---- pair reduction: odd wave -> LDS, even wave sums & stores ----
  if (parity == 1) {
    float* dst = &axl[pairid][lane][0];
    *(float4*)(dst + 0)  = acc0;
    *(float4*)(dst + 4)  = acc1;
    *(float4*)(dst + 8)  = acc2;
    *(float4*)(dst + 12) = acc3;
  }
  __syncthreads();
  if (parity == 0) {
    const float* src = &axl[pairid][lane][0];
    float4 b0 = *(const float4*)(src + 0);
    float4 b1 = *(const float4*)(src + 4);
    float4 b2 = *(const float4*)(src + 8);
    float4 b3 = *(const float4*)(src + 12);
    acc0.x += b0.x; acc0.y += b0.y; acc0.z += b0.z; acc0.w += b0.w;
    acc1.x += b1.x; acc1.y += b1.y; acc1.z += b1.z; acc1.w += b1.w;
    acc2.x += b2.x; acc2.y += b2.y; acc2.z += b2.z; acc2.w += b2.w;
    acc3.x += b3.x; acc3.y += b3.y; acc3.z += b3.z; acc3.w += b3.w;
    float* pb = pacc + ((size_t)bid * NHQ + hkv * 4) * NDH + s32 * 4;
    *(float4*)(pb + 0 * NDH) = acc0;
    *(float4*)(pb + 1 * NDH) = acc1;
    *(float4*)(pb + 2 * NDH) = acc2;
    *(float4*)(pb + 3 * NDH) = acc3;
  }
}

// ---------------------------------------------------------------------------
// Kernel 4: combine 64 chunk partials per (b,hq).  grid 256, block 128.
__global__ __launch_bounds__(128) void attn_combine_k(
    const float* __restrict__ pm, const float* __restrict__ pl,
    const float* __restrict__ pacc, float* __restrict__ aout) {
  int bid = blockIdx.x;
  int b = bid >> 5, hq = bid & 31;
  int d = threadIdx.x;
  float M = -1e30f;
  for (int c = 0; c < NCHUNK; c++)
    M = fmaxf(M, pm[((size_t)(b * NCHUNK + c)) * NHQ + hq]);
  float L = 0.f, o = 0.f;
  for (int c = 0; c < NCHUNK; c++) {
    size_t idx = (size_t)(b * NCHUNK + c) * NHQ + hq;
    float wgt = expf(pm[idx] - M);
    L += wgt * pl[idx];
    o += wgt * pacc[idx * NDH + d];
  }
  aout[(size_t)b * 4096 + hq * NDH + d] = o / L;
}

// ---------------------------------------------------------------------------
// Kernel 5: output projection partials. grid = 8 col-tiles * 64 row-chunks.
__global__ __launch_bounds__(256) void out_partial_k(
    const float* __restrict__ ain, const float* __restrict__ wo,
    float* __restrict__ part) {
  int bid = blockIdx.x;
  int ct = bid & 7, rc = bid >> 3;
  int tid = threadIdx.x;
  __shared__ __align__(16) float xs[RCHUNK][8];
  int rbase = rc * RCHUNK;
  for (int i = tid; i < RCHUNK * 8; i += 256) {
    int b = i >> 6, r = i & 63;
    xs[r][b] = ain[(size_t)b * 4096 + rbase + r];
  }
  __syncthreads();

  int col = ct * 512 + tid * 2;
  const float* wp = wo + (size_t)rbase * 4096 + col;
  float2 acc[8];
#pragma unroll
  for (int b = 0; b < 8; b++) { acc[b].x = 0.f; acc[b].y = 0.f; }
#pragma unroll 8
  for (int r = 0; r < RCHUNK; r++) {
    float2 w2 = *(const float2*)wp; wp += 4096;
    float4 xa = *(const float4*)&xs[r][0];
    float4 xb = *(const float4*)&xs[r][4];
    acc[0].x += xa.x * w2.x; acc[0].y += xa.x * w2.y;
    acc[1].x += xa.y * w2.x; acc[1].y += xa.y * w2.y;
    acc[2].x += xa.z * w2.x; acc[2].y += xa.z * w2.y;
    acc[3].x += xa.w * w2.x; acc[3].y += xa.w * w2.y;
    acc[4].x += xb.x * w2.x; acc[4].y += xb.x * w2.y;
    acc[5].x += xb.y * w2.x; acc[5].y += xb.y * w2.y;
    acc[6].x += xb.z * w2.x; acc[6].y += xb.z * w2.y;
    acc[7].x += xb.w * w2.x; acc[7].y += xb.w * w2.y;
  }
#pragma unroll
  for (int b = 0; b < 8; b++)
    *(float2*)&part[((size_t)rc * 8 + b) * 4096 + col] = acc[b];
}

// ---------------------------------------------------------------------------
// Kernel 6: reduce wo partials + bias -> d_out.  32768 threads.
__global__ __launch_bounds__(256) void out_reduce_k(
    const float* __restrict__ part, const float* __restrict__ bo,
    float* __restrict__ out) {
  int idx = blockIdx.x * 256 + threadIdx.x;
  int b = idx >> 12, col = idx & 4095;
  float s = bo[col];
#pragma unroll 8
  for (int rcc = 0; rcc < NRC; rcc++)
    s += part[((size_t)rcc * 8 + b) * 4096 + col];
  out[idx] = s;
  (void)b;
}

// ---------------------------------------------------------------------------
extern "C" void kernel_launch(void* const* d_in, const int* in_sizes, int n_in,
                              void* d_out, int out_size, void* d_ws, size_t ws_size,
                              hipStream_t stream) {
  const float* x       = (const float*)d_in[0];
  const float* wq      = (const float*)d_in[1];
  const float* bq      = (const float*)d_in[2];
  const float* wk      = (const float*)d_in[3];
  const float* bk      = (const float*)d_in[4];
  const float* wv      = (const float*)d_in[5];
  const float* bv      = (const float*)d_in[6];
  const float* wo      = (const float*)d_in[7];
  const float* bo      = (const float*)d_in[8];
  const float* cache_k = (const float*)d_in[9];
  const float* cache_v = (const float*)d_in[10];
  float* out = (float*)d_out;

  float* ws = (float*)d_ws;
  // region0 [0, 3,145,728): qkv_part(k1w,k2r) -> pacc(k3w,k4r, 2.1M floats)
  //                         -> wo_part(k5w,k6r, 2.1M).  Strictly serial.
  float* qkv_part = ws;
  float* pacc     = ws;
  float* wo_part  = ws;
  float* qws  = ws + 3145728;                 // 32768
  float* kws  = ws + 3178496;                 // 8192
  float* vws  = ws + 3186688;                 // 8192
  float* pm   = ws + 3194880;                 // 16384 (512 blk * 32 hq)
  float* pl   = ws + 3211264;                 // 16384
  float* aout = ws + 3227648;                 // 32768 -> end 3,260,416 (13.0 MB)

  qkv_partial_k<<<768, 256, 0, stream>>>(x, wq, wk, wv, qkv_part);
  qkv_reduce_rope_k<<<192, 256, 0, stream>>>(qkv_part, bq, bk, bv, qws, kws, vws);
  attn_pair_k<<<512, 512, 0, stream>>>(qws, kws, vws, cache_k, cache_v, pm, pl, pacc);
  attn_combine_k<<<256, 128, 0, stream>>>(pm, pl, pacc, aout);
  out_partial_k<<<512, 256, 0, stream>>>(aout, wo, wo_part);
  out_reduce_k<<<128, 256, 0, stream>>>(wo_part, bo, out);
}